// Round 10
// baseline (3342.679 us; speedup 1.0000x reference)
//
#include <hip/hip_runtime.h>
#include <hip/hip_bf16.h>

#define TT 512
#define BB 64
#define HH 512
#define BH (BB*HH)          // 32768
#define TBH ((size_t)TT*BH) // 16777216

typedef __attribute__((ext_vector_type(8)))  short bf16x8;
typedef __attribute__((ext_vector_type(16))) float f32x16;
typedef unsigned int uint;

// split f32[8] -> bf16 hi + bf16 lo of residual
__device__ inline void cvt8(const float* f, bf16x8& hi, bf16x8& lo) {
#pragma unroll
    for (int e = 0; e < 8; ++e) {
        float v = f[e];
        __hip_bfloat16 h = __float2bfloat16(v);
        float hf = __bfloat162float(h);
        __hip_bfloat16 l = __float2bfloat16(v - hf);
        hi[e] = (short)__builtin_bit_cast(unsigned short, h);
        lo[e] = (short)__builtin_bit_cast(unsigned short, l);
    }
}

// f32[8] -> bf16 hi only
__device__ inline void cvt8hi(const float* f, bf16x8& hi) {
#pragma unroll
    for (int e = 0; e < 8; ++e)
        hi[e] = (short)__builtin_bit_cast(unsigned short, __float2bfloat16(f[e]));
}

// unpack 8 packed (hi<<16)|lo dwords held in two uint4s
__device__ inline void unpk44(uint4 a, uint4 b, bf16x8& hi, bf16x8& lo) {
    const uint v[8] = {a.x, a.y, a.z, a.w, b.x, b.y, b.z, b.w};
#pragma unroll
    for (int e = 0; e < 8; ++e) {
        hi[e] = (short)(v[e] >> 16);
        lo[e] = (short)(v[e] & 0xffffu);
    }
}

__device__ inline uint packhl(float v) {
    __hip_bfloat16 h = __float2bfloat16(v);
    float hf = __bfloat162float(h);
    __hip_bfloat16 l = __float2bfloat16(v - hf);
    return ((uint)__builtin_bit_cast(unsigned short, h) << 16)
         |  (uint)__builtin_bit_cast(unsigned short, l);
}

__device__ inline float fsig(float v)  { return 1.f / (1.f + __expf(-v)); }
__device__ inline float ftanh(float v) { return 2.f / (1.f + __expf(-2.f * v)) - 1.f; }

// lane-parallel poll of 32 per-WG flag slots (no RMW, no fences)
__device__ inline void poll32(const int* f, int target, bool loc) {
    const int* p = f + (threadIdx.x & 31);
    for (int it = 0; it < (1 << 22); ++it) {
        int v;
        if (loc) asm volatile("global_load_dword %0, %1, off sc0\n\ts_waitcnt vmcnt(0)"
                              : "=v"(v) : "v"(p) : "memory");
        else     asm volatile("global_load_dword %0, %1, off sc0 sc1\n\ts_waitcnt vmcnt(0)"
                              : "=v"(v) : "v"(p) : "memory");
        if (__all(v >= target)) return;
    }
}

// per-wave poll: wave wv only needs producer slots [8wv, 8wv+8)
__device__ inline void poll8(const int* f, int wv, int target, bool loc) {
    const int* p = f + wv * 8 + (threadIdx.x & 7);
    for (int it = 0; it < (1 << 22); ++it) {
        int v;
        if (loc) asm volatile("global_load_dword %0, %1, off sc0\n\ts_waitcnt vmcnt(0)"
                              : "=v"(v) : "v"(p) : "memory");
        else     asm volatile("global_load_dword %0, %1, off sc0 sc1\n\ts_waitcnt vmcnt(0)"
                              : "=v"(v) : "v"(p) : "memory");
        if (__all(v >= target)) return;
    }
}

__device__ inline void storef(int* p, int v, bool coh) {
    if (coh) asm volatile("global_store_dword %0, %1, off sc0 sc1" :: "v"(p), "v"(v) : "memory");
    else     asm volatile("global_store_dword %0, %1, off"         :: "v"(p), "v"(v) : "memory");
}

__device__ inline void store2(uint* p, uint2 v, bool coh) {
    if (coh) asm volatile("global_store_dwordx2 %0, %1, off sc0 sc1" :: "v"(p), "v"(v) : "memory");
    else     asm volatile("global_store_dwordx2 %0, %1, off sc0"     :: "v"(p), "v"(v) : "memory");
}

#define WAITV0() do { \
    asm volatile("s_waitcnt vmcnt(0)" ::: "memory"); \
    __builtin_amdgcn_sched_barrier(0); } while (0)

// 16 dwordx4 loads covering one wave's 128-dword A-slice
#define ISSUE16(DST, P, LOC) \
    _Pragma("unroll") \
    for (int i = 0; i < 16; ++i) { \
        if (LOC) asm volatile("global_load_dwordx4 %0, %1, off sc0" \
                 : "=v"(DST[i]) : "v"((P) + (i >> 1) * 16 + (i & 1) * 4) : "memory"); \
        else     asm volatile("global_load_dwordx4 %0, %1, off sc0 sc1" \
                 : "=v"(DST[i]) : "v"((P) + (i >> 1) * 16 + (i & 1) * 4) : "memory"); \
    }

// H phase: full 3-term hi/lo
#define MFMA6(WHI, WLO, AHI, ALO, ks) \
    acc00 = __builtin_amdgcn_mfma_f32_32x32x16_bf16(AHI, WHI[0][ks], acc00, 0,0,0); \
    acc10 = __builtin_amdgcn_mfma_f32_32x32x16_bf16(AHI, WHI[1][ks], acc10, 0,0,0); \
    acc01 = __builtin_amdgcn_mfma_f32_32x32x16_bf16(ALO, WHI[0][ks], acc01, 0,0,0); \
    acc01 = __builtin_amdgcn_mfma_f32_32x32x16_bf16(AHI, WLO[0][ks], acc01, 0,0,0); \
    acc11 = __builtin_amdgcn_mfma_f32_32x32x16_bf16(ALO, WHI[1][ks], acc11, 0,0,0); \
    acc11 = __builtin_amdgcn_mfma_f32_32x32x16_bf16(AHI, WLO[1][ks], acc11, 0,0,0);

// X phase: W-hi only, Whi*(ahi + alo)
#define MFMA4X(W0, W1, AHI, ALO) \
    acc00 = __builtin_amdgcn_mfma_f32_32x32x16_bf16(AHI, W0, acc00, 0,0,0); \
    acc10 = __builtin_amdgcn_mfma_f32_32x32x16_bf16(AHI, W1, acc10, 0,0,0); \
    acc01 = __builtin_amdgcn_mfma_f32_32x32x16_bf16(ALO, W0, acc01, 0,0,0); \
    acc11 = __builtin_amdgcn_mfma_f32_32x32x16_bf16(ALO, W1, acc11, 0,0,0);

// Persistent 2-layer LSTM, round 21 (UN-BUNDLED: pad-only on top of r19):
//  - Byte-identical to the VERIFIED 3338us r19 except red pad 17 -> 21.
//    Read bank = 8g + 21c + {10j+k} mod 32 -> ~4-way (was 8-way with 17);
//    odd multiplier keeps writes conflict-free. Pure address change ->
//    bit-exact, provably cannot hang.
//  - r20's x-load hoist is QUARANTINED (timeout suspect: +64 live VGPRs
//    across poll+H region -> spill/codegen pathology). If THIS round times
//    out, the timeout mechanism is infra, not kernel.
__global__ __launch_bounds__(256, 1) void lstm_persist(
    const float* __restrict__ x,
    const float* __restrict__ Wih0, const float* __restrict__ Whh0,
    const float* __restrict__ bih0, const float* __restrict__ bhh0,
    const float* __restrict__ Wih1, const float* __restrict__ Whh1,
    const float* __restrict__ bih1, const float* __restrict__ bhh1,
    float* __restrict__ out, uint* __restrict__ out0pk,
    uint* __restrict__ hring, int* __restrict__ ctrl)
{
    const int tid = threadIdx.x;
    const int bid = blockIdx.x;
    const int resid = bid & 7;
    if (resid >= 4) return;                 // latency-bound: 4 XCDs suffice
    const int cluster = resid;              // 0,1 = layer0 g0/g1 ; 2,3 = layer1
    const int slot = bid >> 3;              // 0..31
    const int layer = cluster >> 1;
    const int grp   = cluster & 1;
    const int colbase = slot * 16;
    const int grp32   = grp * 32;

    const int lane = tid & 63;
    const int wv   = tid >> 6;
    const int mrow = lane & 31;
    const int kh   = lane >> 5;
    const int koff = wv * 128;

    // ---- verify cluster<->XCD integrity (fallback: global coherent mode) ----
    __shared__ int sh_loc;
    {
        int* tab = ctrl + cluster * 32;     // host memset -1
        if (tid == 0) {
            int xcc;
            asm volatile("s_getreg_b32 %0, hwreg(20, 0, 32)" : "=s"(xcc)); // HW_REG_XCC_ID
            asm volatile("global_store_dword %0, %1, off sc0 sc1"
                         :: "v"(tab + slot), "v"(xcc) : "memory");
            asm volatile("s_waitcnt vmcnt(0)" ::: "memory");
            sh_loc = xcc;
        }
        __syncthreads();
        const int myxcc = sh_loc;
        if (tid < 64) {
            int v = -1;
            const int* p = tab + (tid & 31);
            for (int it = 0; it < (1 << 22); ++it) {
                asm volatile("global_load_dword %0, %1, off sc0 sc1\n\ts_waitcnt vmcnt(0)"
                             : "=v"(v) : "v"(p) : "memory");
                if (__all(v != -1)) break;
            }
            const int ok = __all(v == myxcc);
            if (tid == 0) sh_loc = ok;
        }
        __syncthreads();
    }
    const bool loc = sh_loc != 0;

    int* lflags = ctrl + 128 + cluster * 64;   // per-cluster, own 256B line
    int* cflags = ctrl + 384 + grp * 64;       // layer0->layer1 cross flags (L3)

    // ---- weights -> registers, once: W_hh hi+lo (128), W_ih hi (64) ----
    bf16x8 wHhi[2][8], wHlo[2][8], wXhi[2][8];
    {
        const float* Whh = layer ? Whh1 : Whh0;
        const float* Wih = layer ? Wih1 : Wih0;
        const int g = mrow >> 3, cc = mrow & 7;
#pragma unroll
        for (int u = 0; u < 2; ++u) {
            const size_t grow = (size_t)(g * 512 + colbase + u * 8 + cc);
            const float* ph = Whh + grow * 512 + koff + kh * 8;
            const float* px = Wih + grow * 512 + koff + kh * 8;
#pragma unroll
            for (int ks = 0; ks < 8; ++ks) {
                float f[8];
                *(float4*)&f[0] = *(const float4*)(ph + ks * 16);
                *(float4*)&f[4] = *(const float4*)(ph + ks * 16 + 4);
                cvt8(f, wHhi[u][ks], wHlo[u][ks]);
                *(float4*)&f[0] = *(const float4*)(px + ks * 16);
                *(float4*)&f[4] = *(const float4*)(px + ks * 16 + 4);
                cvt8hi(f, wXhi[u][ks]);
            }
        }
    }

    // ---- pointwise: thread owns rows pb, adjacent cols (pc2, pc2+1) ----
    const int pb  = tid >> 3;
    const int pc2 = (tid & 7) * 2;
    const int pu  = pc2 >> 3;
    float bsum[2][4];
    {
        const float* bi = layer ? bih1 : bih0;
        const float* bh = layer ? bhh1 : bhh0;
#pragma unroll
        for (int c = 0; c < 2; ++c)
#pragma unroll
            for (int g = 0; g < 4; ++g) {
                const int r = g * 512 + colbase + pc2 + c;
                bsum[c][g] = bi[r] + bh[r];
            }
    }
    float creg[2] = {0.f, 0.f};
    const int phi = (pb >> 2) & 1;
    const int ri  = (pb & 3) + 4 * (pb >> 3);
    const size_t orow = (size_t)(grp32 + pb) * 512 + colbase + pc2;  // full planes
    const int    hrow = pb * 512 + colbase + pc2;                    // ring (local rows)

    const size_t aoff  = (size_t)(grp32 + mrow) * 512 + koff + kh * 8;
    const size_t hroff = (size_t)mrow * 512 + koff + kh * 8;

    uint* hr = hring + (size_t)cluster * 3 * 16384;   // L2-local packed h ring

    __shared__ float red[4][2][64][21];   // pad 21: reads ~4-way, writes free
    uint2 prevPk = make_uint2(0, 0);

    for (int t = 0; t < TT; ++t) {
        f32x16 acc00 = {0}, acc01 = {0}, acc10 = {0}, acc11 = {0};

        if (layer == 0) {
            // deferred cross publish of plane t-1 (ack hides under this step)
            if (t > 0)
                store2(out0pk + (size_t)(t - 1) * BH + orow, prevPk, true);
            // X phase: plain cached loads of immutable x
            {
                const float* xp = x + (size_t)t * BH + aoff;
                float4 X0[16];
#pragma unroll
                for (int i = 0; i < 16; ++i)
                    X0[i] = *(const float4*)(xp + (i >> 1) * 16 + (i & 1) * 4);
#pragma unroll
                for (int ks = 0; ks < 8; ++ks) {
                    float f[8];
                    *(float4*)&f[0] = X0[2*ks];
                    *(float4*)&f[4] = X0[2*ks + 1];
                    bf16x8 ahi, alo;
                    cvt8(f, ahi, alo);
                    MFMA4X(wXhi[0][ks], wXhi[1][ks], ahi, alo)
                }
            }
            // H phase: per-wave poll of the 8 producer slots this K-slice needs
            if (t > 0) {
                poll8(lflags, wv, t, loc);
                const uint* hp = hr + (size_t)((t - 1) % 3) * 16384 + hroff;
                uint4 H[16];
                ISSUE16(H, hp, loc)
                WAITV0();
#pragma unroll
                for (int ks = 0; ks < 8; ++ks) {
                    bf16x8 ahi, alo;
                    unpk44(H[2*ks], H[2*ks + 1], ahi, alo);
                    MFMA6(wHhi, wHlo, ahi, alo, ks)
                }
            }
        } else {
            // amortized cross wait: planes t..t+3 guaranteed after this
            if ((t & 3) == 0) poll32(cflags, t + 4, false);
            // issue out0pk[t] loads now; consume after H phase
            uint4 XL[16];
            ISSUE16(XL, out0pk + (size_t)t * BH + aoff, false)
            if (t > 0) {
                poll8(lflags, wv, t, loc);
                const uint* hp = hr + (size_t)((t - 1) % 3) * 16384 + hroff; // packed own h
                uint4 HV[16];
                ISSUE16(HV, hp, loc)
                WAITV0();
#pragma unroll
                for (int ks = 0; ks < 8; ++ks) {
                    bf16x8 ahi, alo;
                    unpk44(HV[2*ks], HV[2*ks + 1], ahi, alo);
                    MFMA6(wHhi, wHlo, ahi, alo, ks)
                }
            }
            WAITV0();
#pragma unroll
            for (int ks = 0; ks < 8; ++ks) {
                bf16x8 ahi, alo;
                unpk44(XL[2*ks], XL[2*ks + 1], ahi, alo);
                MFMA4X(wXhi[0][ks], wXhi[1][ks], ahi, alo)
            }
        }

        // ---- cross-wave K reduce ----
#pragma unroll
        for (int r = 0; r < 16; ++r) {
            red[wv][0][lane][r] = acc00[r] + acc01[r];
            red[wv][1][lane][r] = acc10[r] + acc11[r];
        }
        __syncthreads();

        // ---- pointwise LSTM cell (2 adjacent cols) ----
        uint pk2[2];
        float hv2[2];
#pragma unroll
        for (int c = 0; c < 2; ++c) {
            const int n = ((pc2 + c) & 7) + 32 * phi;
            float gate[4];
#pragma unroll
            for (int g = 0; g < 4; ++g) {
                const int nn = g * 8 + n;
                gate[g] = red[0][pu][nn][ri] + red[1][pu][nn][ri]
                        + red[2][pu][nn][ri] + red[3][pu][nn][ri] + bsum[c][g];
            }
            const float si = fsig(gate[0]);
            const float sf = fsig(gate[1]);
            const float tg = ftanh(gate[2]);
            const float so = fsig(gate[3]);
            creg[c] = sf * creg[c] + si * tg;
            hv2[c] = so * ftanh(creg[c]);
            pk2[c] = packhl(hv2[c]);
        }

        // ---- publish h: packed ring for self-consumption (both layers) ----
        store2(hr + (size_t)(t % 3) * 16384 + hrow,
               make_uint2(pk2[0], pk2[1]), !loc);
        if (layer == 0) {
            prevPk = make_uint2(pk2[0], pk2[1]);
        } else {
            float2 hv = make_float2(hv2[0], hv2[1]);
            store2((uint*)(out + (size_t)t * BH + orow),
                   __builtin_bit_cast(uint2, hv), !loc);
        }
        if (t == TT - 1) {
            *(float2*)(out + TBH + (size_t)layer * BH + orow) = make_float2(hv2[0], hv2[1]);
            *(float2*)(out + TBH + 2 * (size_t)BH + (size_t)layer * BH + orow)
                = make_float2(creg[0], creg[1]);
        }

        __syncthreads();   // drains all VMEM (incl. asm stores) + red[] WAR
        if (tid == 0) {
            storef(lflags + slot, t + 1, !loc);        // h(t) ready (L2 or L3)
            if (layer == 0)
                storef(cflags + slot, t, true);        // planes <= t-1 in L3
        }
    }

    // layer-0 tail: publish final out0 plane, then final cross flag
    if (layer == 0) {
        store2(out0pk + (size_t)(TT - 1) * BH + orow, prevPk, true);
        asm volatile("s_waitcnt vmcnt(0)" ::: "memory");
        __syncthreads();
        if (tid == 0) storef(cflags + slot, TT, true);
    }
}

extern "C" void kernel_launch(void* const* d_in, const int* in_sizes, int n_in,
                              void* d_out, int out_size, void* d_ws, size_t ws_size,
                              hipStream_t stream) {
    const float* x    = (const float*)d_in[0];
    const float* Wih0 = (const float*)d_in[1];
    const float* Whh0 = (const float*)d_in[2];
    const float* bih0 = (const float*)d_in[3];
    const float* bhh0 = (const float*)d_in[4];
    const float* Wih1 = (const float*)d_in[5];
    const float* Whh1 = (const float*)d_in[6];
    const float* bih1 = (const float*)d_in[7];
    const float* bhh1 = (const float*)d_in[8];

    float* out    = (float*)d_out;
    uint*  out0pk = (uint*)d_ws;                   // [T,B,H] packed layer-0 h (64 MB)
    uint*  hring  = out0pk + TBH;                  // [4][3][32*512] L2-local rings
    int*   ctrl   = (int*)(hring + 4 * 3 * 16384); // xccTab[128] lflags[256] cflags[128]

    // reset control block each call: xccTab=-1, all flags=-1
    (void)hipMemsetAsync(ctrl, 0xFF, 512 * sizeof(int), stream);

    void* args[] = { (void*)&x, (void*)&Wih0, (void*)&Whh0, (void*)&bih0, (void*)&bhh0,
                     (void*)&Wih1, (void*)&Whh1, (void*)&bih1, (void*)&bhh1,
                     (void*)&out, (void*)&out0pk, (void*)&hring, (void*)&ctrl };
    hipError_t e = hipLaunchCooperativeKernel((const void*)lstm_persist,
                                              dim3(256), dim3(256), args, 0, stream);
    if (e != hipSuccess) {
        // fallback: plain launch — viable because 43KB LDS / ~220 VGPR keeps
        // full-grid residency (all 256 WGs fit 1/CU)
        lstm_persist<<<dim3(256), dim3(256), 0, stream>>>(
            x, Wih0, Whh0, bih0, bhh0, Wih1, Whh1, bih1, bhh1,
            out, out0pk, hring, ctrl);
    }
}

// Round 12
// 3329.317 us; speedup vs baseline: 1.0040x; 1.0040x over previous
//
#include <hip/hip_runtime.h>
#include <hip/hip_bf16.h>

#define TT 512
#define BB 64
#define HH 512
#define BH (BB*HH)          // 32768
#define TBH ((size_t)TT*BH) // 16777216

typedef __attribute__((ext_vector_type(8)))  short bf16x8;
typedef __attribute__((ext_vector_type(16))) float f32x16;
typedef unsigned int uint;

// split f32[8] -> bf16 hi + bf16 lo of residual
__device__ inline void cvt8(const float* f, bf16x8& hi, bf16x8& lo) {
#pragma unroll
    for (int e = 0; e < 8; ++e) {
        float v = f[e];
        __hip_bfloat16 h = __float2bfloat16(v);
        float hf = __bfloat162float(h);
        __hip_bfloat16 l = __float2bfloat16(v - hf);
        hi[e] = (short)__builtin_bit_cast(unsigned short, h);
        lo[e] = (short)__builtin_bit_cast(unsigned short, l);
    }
}

// f32[8] -> bf16 hi only
__device__ inline void cvt8hi(const float* f, bf16x8& hi) {
#pragma unroll
    for (int e = 0; e < 8; ++e)
        hi[e] = (short)__builtin_bit_cast(unsigned short, __float2bfloat16(f[e]));
}

// unpack 8 packed (hi<<16)|lo dwords held in two uint4s
__device__ inline void unpk44(uint4 a, uint4 b, bf16x8& hi, bf16x8& lo) {
    const uint v[8] = {a.x, a.y, a.z, a.w, b.x, b.y, b.z, b.w};
#pragma unroll
    for (int e = 0; e < 8; ++e) {
        hi[e] = (short)(v[e] >> 16);
        lo[e] = (short)(v[e] & 0xffffu);
    }
}

__device__ inline uint packhl(float v) {
    __hip_bfloat16 h = __float2bfloat16(v);
    float hf = __bfloat162float(h);
    __hip_bfloat16 l = __float2bfloat16(v - hf);
    return ((uint)__builtin_bit_cast(unsigned short, h) << 16)
         |  (uint)__builtin_bit_cast(unsigned short, l);
}

__device__ inline float fsig(float v)  { return 1.f / (1.f + __expf(-v)); }
__device__ inline float ftanh(float v) { return 2.f / (1.f + __expf(-2.f * v)) - 1.f; }

// lane-parallel poll of 32 per-WG flag slots (no RMW, no fences)
__device__ inline void poll32(const int* f, int target, bool loc) {
    const int* p = f + (threadIdx.x & 31);
    for (int it = 0; it < (1 << 22); ++it) {
        int v;
        if (loc) asm volatile("global_load_dword %0, %1, off sc0\n\ts_waitcnt vmcnt(0)"
                              : "=v"(v) : "v"(p) : "memory");
        else     asm volatile("global_load_dword %0, %1, off sc0 sc1\n\ts_waitcnt vmcnt(0)"
                              : "=v"(v) : "v"(p) : "memory");
        if (__all(v >= target)) return;
    }
}

// per-wave poll: wave wv only needs producer slots [8wv, 8wv+8)
__device__ inline void poll8(const int* f, int wv, int target, bool loc) {
    const int* p = f + wv * 8 + (threadIdx.x & 7);
    for (int it = 0; it < (1 << 22); ++it) {
        int v;
        if (loc) asm volatile("global_load_dword %0, %1, off sc0\n\ts_waitcnt vmcnt(0)"
                              : "=v"(v) : "v"(p) : "memory");
        else     asm volatile("global_load_dword %0, %1, off sc0 sc1\n\ts_waitcnt vmcnt(0)"
                              : "=v"(v) : "v"(p) : "memory");
        if (__all(v >= target)) return;
    }
}

__device__ inline void storef(int* p, int v, bool coh) {
    if (coh) asm volatile("global_store_dword %0, %1, off sc0 sc1" :: "v"(p), "v"(v) : "memory");
    else     asm volatile("global_store_dword %0, %1, off"         :: "v"(p), "v"(v) : "memory");
}

__device__ inline void store2(uint* p, uint2 v, bool coh) {
    if (coh) asm volatile("global_store_dwordx2 %0, %1, off sc0 sc1" :: "v"(p), "v"(v) : "memory");
    else     asm volatile("global_store_dwordx2 %0, %1, off sc0"     :: "v"(p), "v"(v) : "memory");
}

#define WAITV0() do { \
    asm volatile("s_waitcnt vmcnt(0)" ::: "memory"); \
    __builtin_amdgcn_sched_barrier(0); } while (0)

// 16 dwordx4 loads covering one wave's 128-dword A-slice
#define ISSUE16(DST, P, LOC) \
    _Pragma("unroll") \
    for (int i = 0; i < 16; ++i) { \
        if (LOC) asm volatile("global_load_dwordx4 %0, %1, off sc0" \
                 : "=v"(DST[i]) : "v"((P) + (i >> 1) * 16 + (i & 1) * 4) : "memory"); \
        else     asm volatile("global_load_dwordx4 %0, %1, off sc0 sc1" \
                 : "=v"(DST[i]) : "v"((P) + (i >> 1) * 16 + (i & 1) * 4) : "memory"); \
    }

// H phase: full 3-term hi/lo
#define MFMA6(WHI, WLO, AHI, ALO, ks) \
    acc00 = __builtin_amdgcn_mfma_f32_32x32x16_bf16(AHI, WHI[0][ks], acc00, 0,0,0); \
    acc10 = __builtin_amdgcn_mfma_f32_32x32x16_bf16(AHI, WHI[1][ks], acc10, 0,0,0); \
    acc01 = __builtin_amdgcn_mfma_f32_32x32x16_bf16(ALO, WHI[0][ks], acc01, 0,0,0); \
    acc01 = __builtin_amdgcn_mfma_f32_32x32x16_bf16(AHI, WLO[0][ks], acc01, 0,0,0); \
    acc11 = __builtin_amdgcn_mfma_f32_32x32x16_bf16(ALO, WHI[1][ks], acc11, 0,0,0); \
    acc11 = __builtin_amdgcn_mfma_f32_32x32x16_bf16(AHI, WLO[1][ks], acc11, 0,0,0);

// X phase: W-hi only, Whi*(ahi + alo)
#define MFMA4X(W0, W1, AHI, ALO) \
    acc00 = __builtin_amdgcn_mfma_f32_32x32x16_bf16(AHI, W0, acc00, 0,0,0); \
    acc10 = __builtin_amdgcn_mfma_f32_32x32x16_bf16(AHI, W1, acc10, 0,0,0); \
    acc01 = __builtin_amdgcn_mfma_f32_32x32x16_bf16(ALO, W0, acc01, 0,0,0); \
    acc11 = __builtin_amdgcn_mfma_f32_32x32x16_bf16(ALO, W1, acc11, 0,0,0);

// Persistent 2-layer LSTM, FINAL (= verified round-19 build, 3338us):
//  - 4 XCD-pinned clusters x 32 slots (layer0 g0/g1, layer1 g0/g1), runtime
//    XCD-integrity check with coherent-mode fallback.
//  - Banked deltas vs the 3546us session baseline: layer-1 self-consumes its
//    PACKED h ring (bit-identical numerics, no per-step cvt8 on layer-1's
//    recurrence chain); per-wave poll8 (straggler decoupling).
//  - Empirically rejected this session (all verified on HW): xg precompute
//    consumption (r12-r16: data+protocol proven clean, consumption fails
//    deterministically for unlocalized cadence reasons); non-bit-exact
//    MFMA reordering (r17: 4x error compounding over 512 steps); pre-barrier
//    early flags (r18: timeout); red repad 17->21 (r21: SQ_LDS_BANK_CONFLICT
//    invariant, neutral); layer-0 x-load hoist in both plain-C++ (r20) and
//    asm (r22) forms (timeouts, suspected regalloc pathology with ~384 live
//    VGPRs across the poll loop).
//  - Remaining floor: inter-WG recurrence edge + in-step serial chain,
//    ~6.5us/step at 0.74% HBM / 7% MfmaUtil (latency-bound).
__global__ __launch_bounds__(256, 1) void lstm_persist(
    const float* __restrict__ x,
    const float* __restrict__ Wih0, const float* __restrict__ Whh0,
    const float* __restrict__ bih0, const float* __restrict__ bhh0,
    const float* __restrict__ Wih1, const float* __restrict__ Whh1,
    const float* __restrict__ bih1, const float* __restrict__ bhh1,
    float* __restrict__ out, uint* __restrict__ out0pk,
    uint* __restrict__ hring, int* __restrict__ ctrl)
{
    const int tid = threadIdx.x;
    const int bid = blockIdx.x;
    const int resid = bid & 7;
    if (resid >= 4) return;                 // latency-bound: 4 XCDs suffice
    const int cluster = resid;              // 0,1 = layer0 g0/g1 ; 2,3 = layer1
    const int slot = bid >> 3;              // 0..31
    const int layer = cluster >> 1;
    const int grp   = cluster & 1;
    const int colbase = slot * 16;
    const int grp32   = grp * 32;

    const int lane = tid & 63;
    const int wv   = tid >> 6;
    const int mrow = lane & 31;
    const int kh   = lane >> 5;
    const int koff = wv * 128;

    // ---- verify cluster<->XCD integrity (fallback: global coherent mode) ----
    __shared__ int sh_loc;
    {
        int* tab = ctrl + cluster * 32;     // host memset -1
        if (tid == 0) {
            int xcc;
            asm volatile("s_getreg_b32 %0, hwreg(20, 0, 32)" : "=s"(xcc)); // HW_REG_XCC_ID
            asm volatile("global_store_dword %0, %1, off sc0 sc1"
                         :: "v"(tab + slot), "v"(xcc) : "memory");
            asm volatile("s_waitcnt vmcnt(0)" ::: "memory");
            sh_loc = xcc;
        }
        __syncthreads();
        const int myxcc = sh_loc;
        if (tid < 64) {
            int v = -1;
            const int* p = tab + (tid & 31);
            for (int it = 0; it < (1 << 22); ++it) {
                asm volatile("global_load_dword %0, %1, off sc0 sc1\n\ts_waitcnt vmcnt(0)"
                             : "=v"(v) : "v"(p) : "memory");
                if (__all(v != -1)) break;
            }
            const int ok = __all(v == myxcc);
            if (tid == 0) sh_loc = ok;
        }
        __syncthreads();
    }
    const bool loc = sh_loc != 0;

    int* lflags = ctrl + 128 + cluster * 64;   // per-cluster, own 256B line
    int* cflags = ctrl + 384 + grp * 64;       // layer0->layer1 cross flags (L3)

    // ---- weights -> registers, once: W_hh hi+lo (128), W_ih hi (64) ----
    bf16x8 wHhi[2][8], wHlo[2][8], wXhi[2][8];
    {
        const float* Whh = layer ? Whh1 : Whh0;
        const float* Wih = layer ? Wih1 : Wih0;
        const int g = mrow >> 3, cc = mrow & 7;
#pragma unroll
        for (int u = 0; u < 2; ++u) {
            const size_t grow = (size_t)(g * 512 + colbase + u * 8 + cc);
            const float* ph = Whh + grow * 512 + koff + kh * 8;
            const float* px = Wih + grow * 512 + koff + kh * 8;
#pragma unroll
            for (int ks = 0; ks < 8; ++ks) {
                float f[8];
                *(float4*)&f[0] = *(const float4*)(ph + ks * 16);
                *(float4*)&f[4] = *(const float4*)(ph + ks * 16 + 4);
                cvt8(f, wHhi[u][ks], wHlo[u][ks]);
                *(float4*)&f[0] = *(const float4*)(px + ks * 16);
                *(float4*)&f[4] = *(const float4*)(px + ks * 16 + 4);
                cvt8hi(f, wXhi[u][ks]);
            }
        }
    }

    // ---- pointwise: thread owns rows pb, adjacent cols (pc2, pc2+1) ----
    const int pb  = tid >> 3;
    const int pc2 = (tid & 7) * 2;
    const int pu  = pc2 >> 3;
    float bsum[2][4];
    {
        const float* bi = layer ? bih1 : bih0;
        const float* bh = layer ? bhh1 : bhh0;
#pragma unroll
        for (int c = 0; c < 2; ++c)
#pragma unroll
            for (int g = 0; g < 4; ++g) {
                const int r = g * 512 + colbase + pc2 + c;
                bsum[c][g] = bi[r] + bh[r];
            }
    }
    float creg[2] = {0.f, 0.f};
    const int phi = (pb >> 2) & 1;
    const int ri  = (pb & 3) + 4 * (pb >> 3);
    const size_t orow = (size_t)(grp32 + pb) * 512 + colbase + pc2;  // full planes
    const int    hrow = pb * 512 + colbase + pc2;                    // ring (local rows)

    const size_t aoff  = (size_t)(grp32 + mrow) * 512 + koff + kh * 8;
    const size_t hroff = (size_t)mrow * 512 + koff + kh * 8;

    uint* hr = hring + (size_t)cluster * 3 * 16384;   // L2-local packed h ring

    __shared__ float red[4][2][64][17];
    uint2 prevPk = make_uint2(0, 0);

    for (int t = 0; t < TT; ++t) {
        f32x16 acc00 = {0}, acc01 = {0}, acc10 = {0}, acc11 = {0};

        if (layer == 0) {
            // deferred cross publish of plane t-1 (ack hides under this step)
            if (t > 0)
                store2(out0pk + (size_t)(t - 1) * BH + orow, prevPk, true);
            // X phase: plain cached loads of immutable x
            {
                const float* xp = x + (size_t)t * BH + aoff;
                float4 X0[16];
#pragma unroll
                for (int i = 0; i < 16; ++i)
                    X0[i] = *(const float4*)(xp + (i >> 1) * 16 + (i & 1) * 4);
#pragma unroll
                for (int ks = 0; ks < 8; ++ks) {
                    float f[8];
                    *(float4*)&f[0] = X0[2*ks];
                    *(float4*)&f[4] = X0[2*ks + 1];
                    bf16x8 ahi, alo;
                    cvt8(f, ahi, alo);
                    MFMA4X(wXhi[0][ks], wXhi[1][ks], ahi, alo)
                }
            }
            // H phase: per-wave poll of the 8 producer slots this K-slice needs
            if (t > 0) {
                poll8(lflags, wv, t, loc);
                const uint* hp = hr + (size_t)((t - 1) % 3) * 16384 + hroff;
                uint4 H[16];
                ISSUE16(H, hp, loc)
                WAITV0();
#pragma unroll
                for (int ks = 0; ks < 8; ++ks) {
                    bf16x8 ahi, alo;
                    unpk44(H[2*ks], H[2*ks + 1], ahi, alo);
                    MFMA6(wHhi, wHlo, ahi, alo, ks)
                }
            }
        } else {
            // amortized cross wait: planes t..t+3 guaranteed after this
            if ((t & 3) == 0) poll32(cflags, t + 4, false);
            // issue out0pk[t] loads now; consume after H phase
            uint4 XL[16];
            ISSUE16(XL, out0pk + (size_t)t * BH + aoff, false)
            if (t > 0) {
                poll8(lflags, wv, t, loc);
                const uint* hp = hr + (size_t)((t - 1) % 3) * 16384 + hroff; // packed own h
                uint4 HV[16];
                ISSUE16(HV, hp, loc)
                WAITV0();
#pragma unroll
                for (int ks = 0; ks < 8; ++ks) {
                    bf16x8 ahi, alo;
                    unpk44(HV[2*ks], HV[2*ks + 1], ahi, alo);
                    MFMA6(wHhi, wHlo, ahi, alo, ks)
                }
            }
            WAITV0();
#pragma unroll
            for (int ks = 0; ks < 8; ++ks) {
                bf16x8 ahi, alo;
                unpk44(XL[2*ks], XL[2*ks + 1], ahi, alo);
                MFMA4X(wXhi[0][ks], wXhi[1][ks], ahi, alo)
            }
        }

        // ---- cross-wave K reduce ----
#pragma unroll
        for (int r = 0; r < 16; ++r) {
            red[wv][0][lane][r] = acc00[r] + acc01[r];
            red[wv][1][lane][r] = acc10[r] + acc11[r];
        }
        __syncthreads();

        // ---- pointwise LSTM cell (2 adjacent cols) ----
        uint pk2[2];
        float hv2[2];
#pragma unroll
        for (int c = 0; c < 2; ++c) {
            const int n = ((pc2 + c) & 7) + 32 * phi;
            float gate[4];
#pragma unroll
            for (int g = 0; g < 4; ++g) {
                const int nn = g * 8 + n;
                gate[g] = red[0][pu][nn][ri] + red[1][pu][nn][ri]
                        + red[2][pu][nn][ri] + red[3][pu][nn][ri] + bsum[c][g];
            }
            const float si = fsig(gate[0]);
            const float sf = fsig(gate[1]);
            const float tg = ftanh(gate[2]);
            const float so = fsig(gate[3]);
            creg[c] = sf * creg[c] + si * tg;
            hv2[c] = so * ftanh(creg[c]);
            pk2[c] = packhl(hv2[c]);
        }

        // ---- publish h: packed ring for self-consumption (both layers) ----
        store2(hr + (size_t)(t % 3) * 16384 + hrow,
               make_uint2(pk2[0], pk2[1]), !loc);
        if (layer == 0) {
            prevPk = make_uint2(pk2[0], pk2[1]);
        } else {
            float2 hv = make_float2(hv2[0], hv2[1]);
            store2((uint*)(out + (size_t)t * BH + orow),
                   __builtin_bit_cast(uint2, hv), !loc);
        }
        if (t == TT - 1) {
            *(float2*)(out + TBH + (size_t)layer * BH + orow) = make_float2(hv2[0], hv2[1]);
            *(float2*)(out + TBH + 2 * (size_t)BH + (size_t)layer * BH + orow)
                = make_float2(creg[0], creg[1]);
        }

        __syncthreads();   // drains all VMEM (incl. asm stores) + red[] WAR
        if (tid == 0) {
            storef(lflags + slot, t + 1, !loc);        // h(t) ready (L2 or L3)
            if (layer == 0)
                storef(cflags + slot, t, true);        // planes <= t-1 in L3
        }
    }

    // layer-0 tail: publish final out0 plane, then final cross flag
    if (layer == 0) {
        store2(out0pk + (size_t)(TT - 1) * BH + orow, prevPk, true);
        asm volatile("s_waitcnt vmcnt(0)" ::: "memory");
        __syncthreads();
        if (tid == 0) storef(cflags + slot, TT, true);
    }
}

extern "C" void kernel_launch(void* const* d_in, const int* in_sizes, int n_in,
                              void* d_out, int out_size, void* d_ws, size_t ws_size,
                              hipStream_t stream) {
    const float* x    = (const float*)d_in[0];
    const float* Wih0 = (const float*)d_in[1];
    const float* Whh0 = (const float*)d_in[2];
    const float* bih0 = (const float*)d_in[3];
    const float* bhh0 = (const float*)d_in[4];
    const float* Wih1 = (const float*)d_in[5];
    const float* Whh1 = (const float*)d_in[6];
    const float* bih1 = (const float*)d_in[7];
    const float* bhh1 = (const float*)d_in[8];

    float* out    = (float*)d_out;
    uint*  out0pk = (uint*)d_ws;                   // [T,B,H] packed layer-0 h (64 MB)
    uint*  hring  = out0pk + TBH;                  // [4][3][32*512] L2-local rings
    int*   ctrl   = (int*)(hring + 4 * 3 * 16384); // xccTab[128] lflags[256] cflags[128]

    // reset control block each call: xccTab=-1, all flags=-1
    (void)hipMemsetAsync(ctrl, 0xFF, 512 * sizeof(int), stream);

    void* args[] = { (void*)&x, (void*)&Wih0, (void*)&Whh0, (void*)&bih0, (void*)&bhh0,
                     (void*)&Wih1, (void*)&Whh1, (void*)&bih1, (void*)&bhh1,
                     (void*)&out, (void*)&out0pk, (void*)&hring, (void*)&ctrl };
    hipError_t e = hipLaunchCooperativeKernel((const void*)lstm_persist,
                                              dim3(256), dim3(256), args, 0, stream);
    if (e != hipSuccess) {
        // fallback: plain launch — viable because 35KB LDS / ~220 VGPR keeps
        // full-grid residency (all 256 WGs fit 1/CU)
        lstm_persist<<<dim3(256), dim3(256), 0, stream>>>(
            x, Wih0, Whh0, bih0, bhh0, Wih1, Whh1, bih1, bhh1,
            out, out0pk, hring, ctrl);
    }
}

// Round 13
// 3326.134 us; speedup vs baseline: 1.0050x; 1.0010x over previous
//
#include <hip/hip_runtime.h>
#include <hip/hip_bf16.h>

#define TT 512
#define BB 64
#define HH 512
#define BH (BB*HH)          // 32768
#define TBH ((size_t)TT*BH) // 16777216

typedef __attribute__((ext_vector_type(8)))  short bf16x8;
typedef __attribute__((ext_vector_type(16))) float f32x16;
typedef unsigned int uint;

// split f32[8] -> bf16 hi + bf16 lo of residual
__device__ inline void cvt8(const float* f, bf16x8& hi, bf16x8& lo) {
#pragma unroll
    for (int e = 0; e < 8; ++e) {
        float v = f[e];
        __hip_bfloat16 h = __float2bfloat16(v);
        float hf = __bfloat162float(h);
        __hip_bfloat16 l = __float2bfloat16(v - hf);
        hi[e] = (short)__builtin_bit_cast(unsigned short, h);
        lo[e] = (short)__builtin_bit_cast(unsigned short, l);
    }
}

// f32[8] -> bf16 hi only
__device__ inline void cvt8hi(const float* f, bf16x8& hi) {
#pragma unroll
    for (int e = 0; e < 8; ++e)
        hi[e] = (short)__builtin_bit_cast(unsigned short, __float2bfloat16(f[e]));
}

// unpack 8 packed (hi<<16)|lo dwords held in two uint4s
__device__ inline void unpk44(uint4 a, uint4 b, bf16x8& hi, bf16x8& lo) {
    const uint v[8] = {a.x, a.y, a.z, a.w, b.x, b.y, b.z, b.w};
#pragma unroll
    for (int e = 0; e < 8; ++e) {
        hi[e] = (short)(v[e] >> 16);
        lo[e] = (short)(v[e] & 0xffffu);
    }
}

__device__ inline uint packhl(float v) {
    __hip_bfloat16 h = __float2bfloat16(v);
    float hf = __bfloat162float(h);
    __hip_bfloat16 l = __float2bfloat16(v - hf);
    return ((uint)__builtin_bit_cast(unsigned short, h) << 16)
         |  (uint)__builtin_bit_cast(unsigned short, l);
}

__device__ inline float fsig(float v)  { return 1.f / (1.f + __expf(-v)); }
__device__ inline float ftanh(float v) { return 2.f / (1.f + __expf(-2.f * v)) - 1.f; }

// lane-parallel poll of 32 per-WG flag slots (no RMW, no fences)
__device__ inline void poll32(const int* f, int target, bool loc) {
    const int* p = f + (threadIdx.x & 31);
    for (int it = 0; it < (1 << 22); ++it) {
        int v;
        if (loc) asm volatile("global_load_dword %0, %1, off sc0\n\ts_waitcnt vmcnt(0)"
                              : "=v"(v) : "v"(p) : "memory");
        else     asm volatile("global_load_dword %0, %1, off sc0 sc1\n\ts_waitcnt vmcnt(0)"
                              : "=v"(v) : "v"(p) : "memory");
        if (__all(v >= target)) return;
    }
}

// per-wave poll: wave wv only needs producer slots [8wv, 8wv+8)
__device__ inline void poll8(const int* f, int wv, int target, bool loc) {
    const int* p = f + wv * 8 + (threadIdx.x & 7);
    for (int it = 0; it < (1 << 22); ++it) {
        int v;
        if (loc) asm volatile("global_load_dword %0, %1, off sc0\n\ts_waitcnt vmcnt(0)"
                              : "=v"(v) : "v"(p) : "memory");
        else     asm volatile("global_load_dword %0, %1, off sc0 sc1\n\ts_waitcnt vmcnt(0)"
                              : "=v"(v) : "v"(p) : "memory");
        if (__all(v >= target)) return;
    }
}

__device__ inline void storef(int* p, int v, bool coh) {
    if (coh) asm volatile("global_store_dword %0, %1, off sc0 sc1" :: "v"(p), "v"(v) : "memory");
    else     asm volatile("global_store_dword %0, %1, off"         :: "v"(p), "v"(v) : "memory");
}

__device__ inline void store2(uint* p, uint2 v, bool coh) {
    if (coh) asm volatile("global_store_dwordx2 %0, %1, off sc0 sc1" :: "v"(p), "v"(v) : "memory");
    else     asm volatile("global_store_dwordx2 %0, %1, off sc0"     :: "v"(p), "v"(v) : "memory");
}

#define WAITV0() do { \
    asm volatile("s_waitcnt vmcnt(0)" ::: "memory"); \
    __builtin_amdgcn_sched_barrier(0); } while (0)

// 16 dwordx4 loads covering one wave's 128-dword A-slice
#define ISSUE16(DST, P, LOC) \
    _Pragma("unroll") \
    for (int i = 0; i < 16; ++i) { \
        if (LOC) asm volatile("global_load_dwordx4 %0, %1, off sc0" \
                 : "=v"(DST[i]) : "v"((P) + (i >> 1) * 16 + (i & 1) * 4) : "memory"); \
        else     asm volatile("global_load_dwordx4 %0, %1, off sc0 sc1" \
                 : "=v"(DST[i]) : "v"((P) + (i >> 1) * 16 + (i & 1) * 4) : "memory"); \
    }

// H phase: full 3-term hi/lo
#define MFMA6(WHI, WLO, AHI, ALO, ks) \
    acc00 = __builtin_amdgcn_mfma_f32_32x32x16_bf16(AHI, WHI[0][ks], acc00, 0,0,0); \
    acc10 = __builtin_amdgcn_mfma_f32_32x32x16_bf16(AHI, WHI[1][ks], acc10, 0,0,0); \
    acc01 = __builtin_amdgcn_mfma_f32_32x32x16_bf16(ALO, WHI[0][ks], acc01, 0,0,0); \
    acc01 = __builtin_amdgcn_mfma_f32_32x32x16_bf16(AHI, WLO[0][ks], acc01, 0,0,0); \
    acc11 = __builtin_amdgcn_mfma_f32_32x32x16_bf16(ALO, WHI[1][ks], acc11, 0,0,0); \
    acc11 = __builtin_amdgcn_mfma_f32_32x32x16_bf16(AHI, WLO[1][ks], acc11, 0,0,0);

// X phase: W-hi only, Whi*(ahi + alo)
#define MFMA4X(W0, W1, AHI, ALO) \
    acc00 = __builtin_amdgcn_mfma_f32_32x32x16_bf16(AHI, W0, acc00, 0,0,0); \
    acc10 = __builtin_amdgcn_mfma_f32_32x32x16_bf16(AHI, W1, acc10, 0,0,0); \
    acc01 = __builtin_amdgcn_mfma_f32_32x32x16_bf16(ALO, W0, acc01, 0,0,0); \
    acc11 = __builtin_amdgcn_mfma_f32_32x32x16_bf16(ALO, W1, acc11, 0,0,0);

// Persistent 2-layer LSTM, round 24 (= verified r19 + layer-1 out-store
// deferred past the end-of-step barrier):
//  - The out[t] store is fire-and-forget (never read, never rewritten).
//    Issuing it AFTER __syncthreads removes its HBM write-ack (~600-900cy)
//    from layer-1's per-step barrier drain; it is drained by the NEXT
//    step's barrier where it overlaps a full step of compute. Store motion
//    across a barrier with zero readers: no protocol/numeric/flag change.
//  - Everything else byte-identical to the verified 3329us r19 build.
//  - Session record of rejected levers (all HW-verified): xg precompute
//    consumption (r12-r16), non-bit-exact MFMA reorder (r17), pre-barrier
//    early flags (r18), red repad (r21, SQ_LDS_BANK_CONFLICT invariant),
//    layer-0 x-load hoist plain-C++ (r20) and asm (r22) — timeouts.
//  - Remaining floor: inter-WG flag->poll recurrence edge, ~7.3us/step,
//    latency-bound (HBM 0.74%, MfmaUtil 7.3%).
__global__ __launch_bounds__(256, 1) void lstm_persist(
    const float* __restrict__ x,
    const float* __restrict__ Wih0, const float* __restrict__ Whh0,
    const float* __restrict__ bih0, const float* __restrict__ bhh0,
    const float* __restrict__ Wih1, const float* __restrict__ Whh1,
    const float* __restrict__ bih1, const float* __restrict__ bhh1,
    float* __restrict__ out, uint* __restrict__ out0pk,
    uint* __restrict__ hring, int* __restrict__ ctrl)
{
    const int tid = threadIdx.x;
    const int bid = blockIdx.x;
    const int resid = bid & 7;
    if (resid >= 4) return;                 // latency-bound: 4 XCDs suffice
    const int cluster = resid;              // 0,1 = layer0 g0/g1 ; 2,3 = layer1
    const int slot = bid >> 3;              // 0..31
    const int layer = cluster >> 1;
    const int grp   = cluster & 1;
    const int colbase = slot * 16;
    const int grp32   = grp * 32;

    const int lane = tid & 63;
    const int wv   = tid >> 6;
    const int mrow = lane & 31;
    const int kh   = lane >> 5;
    const int koff = wv * 128;

    // ---- verify cluster<->XCD integrity (fallback: global coherent mode) ----
    __shared__ int sh_loc;
    {
        int* tab = ctrl + cluster * 32;     // host memset -1
        if (tid == 0) {
            int xcc;
            asm volatile("s_getreg_b32 %0, hwreg(20, 0, 32)" : "=s"(xcc)); // HW_REG_XCC_ID
            asm volatile("global_store_dword %0, %1, off sc0 sc1"
                         :: "v"(tab + slot), "v"(xcc) : "memory");
            asm volatile("s_waitcnt vmcnt(0)" ::: "memory");
            sh_loc = xcc;
        }
        __syncthreads();
        const int myxcc = sh_loc;
        if (tid < 64) {
            int v = -1;
            const int* p = tab + (tid & 31);
            for (int it = 0; it < (1 << 22); ++it) {
                asm volatile("global_load_dword %0, %1, off sc0 sc1\n\ts_waitcnt vmcnt(0)"
                             : "=v"(v) : "v"(p) : "memory");
                if (__all(v != -1)) break;
            }
            const int ok = __all(v == myxcc);
            if (tid == 0) sh_loc = ok;
        }
        __syncthreads();
    }
    const bool loc = sh_loc != 0;

    int* lflags = ctrl + 128 + cluster * 64;   // per-cluster, own 256B line
    int* cflags = ctrl + 384 + grp * 64;       // layer0->layer1 cross flags (L3)

    // ---- weights -> registers, once: W_hh hi+lo (128), W_ih hi (64) ----
    bf16x8 wHhi[2][8], wHlo[2][8], wXhi[2][8];
    {
        const float* Whh = layer ? Whh1 : Whh0;
        const float* Wih = layer ? Wih1 : Wih0;
        const int g = mrow >> 3, cc = mrow & 7;
#pragma unroll
        for (int u = 0; u < 2; ++u) {
            const size_t grow = (size_t)(g * 512 + colbase + u * 8 + cc);
            const float* ph = Whh + grow * 512 + koff + kh * 8;
            const float* px = Wih + grow * 512 + koff + kh * 8;
#pragma unroll
            for (int ks = 0; ks < 8; ++ks) {
                float f[8];
                *(float4*)&f[0] = *(const float4*)(ph + ks * 16);
                *(float4*)&f[4] = *(const float4*)(ph + ks * 16 + 4);
                cvt8(f, wHhi[u][ks], wHlo[u][ks]);
                *(float4*)&f[0] = *(const float4*)(px + ks * 16);
                *(float4*)&f[4] = *(const float4*)(px + ks * 16 + 4);
                cvt8hi(f, wXhi[u][ks]);
            }
        }
    }

    // ---- pointwise: thread owns rows pb, adjacent cols (pc2, pc2+1) ----
    const int pb  = tid >> 3;
    const int pc2 = (tid & 7) * 2;
    const int pu  = pc2 >> 3;
    float bsum[2][4];
    {
        const float* bi = layer ? bih1 : bih0;
        const float* bh = layer ? bhh1 : bhh0;
#pragma unroll
        for (int c = 0; c < 2; ++c)
#pragma unroll
            for (int g = 0; g < 4; ++g) {
                const int r = g * 512 + colbase + pc2 + c;
                bsum[c][g] = bi[r] + bh[r];
            }
    }
    float creg[2] = {0.f, 0.f};
    const int phi = (pb >> 2) & 1;
    const int ri  = (pb & 3) + 4 * (pb >> 3);
    const size_t orow = (size_t)(grp32 + pb) * 512 + colbase + pc2;  // full planes
    const int    hrow = pb * 512 + colbase + pc2;                    // ring (local rows)

    const size_t aoff  = (size_t)(grp32 + mrow) * 512 + koff + kh * 8;
    const size_t hroff = (size_t)mrow * 512 + koff + kh * 8;

    uint* hr = hring + (size_t)cluster * 3 * 16384;   // L2-local packed h ring

    __shared__ float red[4][2][64][17];
    uint2 prevPk = make_uint2(0, 0);

    for (int t = 0; t < TT; ++t) {
        f32x16 acc00 = {0}, acc01 = {0}, acc10 = {0}, acc11 = {0};

        if (layer == 0) {
            // deferred cross publish of plane t-1 (ack hides under this step)
            if (t > 0)
                store2(out0pk + (size_t)(t - 1) * BH + orow, prevPk, true);
            // X phase: plain cached loads of immutable x
            {
                const float* xp = x + (size_t)t * BH + aoff;
                float4 X0[16];
#pragma unroll
                for (int i = 0; i < 16; ++i)
                    X0[i] = *(const float4*)(xp + (i >> 1) * 16 + (i & 1) * 4);
#pragma unroll
                for (int ks = 0; ks < 8; ++ks) {
                    float f[8];
                    *(float4*)&f[0] = X0[2*ks];
                    *(float4*)&f[4] = X0[2*ks + 1];
                    bf16x8 ahi, alo;
                    cvt8(f, ahi, alo);
                    MFMA4X(wXhi[0][ks], wXhi[1][ks], ahi, alo)
                }
            }
            // H phase: per-wave poll of the 8 producer slots this K-slice needs
            if (t > 0) {
                poll8(lflags, wv, t, loc);
                const uint* hp = hr + (size_t)((t - 1) % 3) * 16384 + hroff;
                uint4 H[16];
                ISSUE16(H, hp, loc)
                WAITV0();
#pragma unroll
                for (int ks = 0; ks < 8; ++ks) {
                    bf16x8 ahi, alo;
                    unpk44(H[2*ks], H[2*ks + 1], ahi, alo);
                    MFMA6(wHhi, wHlo, ahi, alo, ks)
                }
            }
        } else {
            // amortized cross wait: planes t..t+3 guaranteed after this
            if ((t & 3) == 0) poll32(cflags, t + 4, false);
            // issue out0pk[t] loads now; consume after H phase
            uint4 XL[16];
            ISSUE16(XL, out0pk + (size_t)t * BH + aoff, false)
            if (t > 0) {
                poll8(lflags, wv, t, loc);
                const uint* hp = hr + (size_t)((t - 1) % 3) * 16384 + hroff; // packed own h
                uint4 HV[16];
                ISSUE16(HV, hp, loc)
                WAITV0();
#pragma unroll
                for (int ks = 0; ks < 8; ++ks) {
                    bf16x8 ahi, alo;
                    unpk44(HV[2*ks], HV[2*ks + 1], ahi, alo);
                    MFMA6(wHhi, wHlo, ahi, alo, ks)
                }
            }
            WAITV0();
#pragma unroll
            for (int ks = 0; ks < 8; ++ks) {
                bf16x8 ahi, alo;
                unpk44(XL[2*ks], XL[2*ks + 1], ahi, alo);
                MFMA4X(wXhi[0][ks], wXhi[1][ks], ahi, alo)
            }
        }

        // ---- cross-wave K reduce ----
#pragma unroll
        for (int r = 0; r < 16; ++r) {
            red[wv][0][lane][r] = acc00[r] + acc01[r];
            red[wv][1][lane][r] = acc10[r] + acc11[r];
        }
        __syncthreads();

        // ---- pointwise LSTM cell (2 adjacent cols) ----
        uint pk2[2];
        float hv2[2];
#pragma unroll
        for (int c = 0; c < 2; ++c) {
            const int n = ((pc2 + c) & 7) + 32 * phi;
            float gate[4];
#pragma unroll
            for (int g = 0; g < 4; ++g) {
                const int nn = g * 8 + n;
                gate[g] = red[0][pu][nn][ri] + red[1][pu][nn][ri]
                        + red[2][pu][nn][ri] + red[3][pu][nn][ri] + bsum[c][g];
            }
            const float si = fsig(gate[0]);
            const float sf = fsig(gate[1]);
            const float tg = ftanh(gate[2]);
            const float so = fsig(gate[3]);
            creg[c] = sf * creg[c] + si * tg;
            hv2[c] = so * ftanh(creg[c]);
            pk2[c] = packhl(hv2[c]);
        }

        // ---- publish h: packed ring (flag-guarded, must precede barrier) ----
        store2(hr + (size_t)(t % 3) * 16384 + hrow,
               make_uint2(pk2[0], pk2[1]), !loc);
        if (layer == 0)
            prevPk = make_uint2(pk2[0], pk2[1]);
        if (t == TT - 1) {
            *(float2*)(out + TBH + (size_t)layer * BH + orow) = make_float2(hv2[0], hv2[1]);
            *(float2*)(out + TBH + 2 * (size_t)BH + (size_t)layer * BH + orow)
                = make_float2(creg[0], creg[1]);
        }

        __syncthreads();   // drains h-ring store (flag guard) + red[] WAR

        // deferred fire-and-forget out[t] store: never read, never rewritten;
        // drained by the NEXT step's barrier (overlaps a full step) or by
        // kernel completion for t = TT-1.
        if (layer == 1) {
            float2 hv = make_float2(hv2[0], hv2[1]);
            store2((uint*)(out + (size_t)t * BH + orow),
                   __builtin_bit_cast(uint2, hv), !loc);
        }
        if (tid == 0) {
            storef(lflags + slot, t + 1, !loc);        // h(t) ready (L2 or L3)
            if (layer == 0)
                storef(cflags + slot, t, true);        // planes <= t-1 in L3
        }
    }

    // layer-0 tail: publish final out0 plane, then final cross flag
    if (layer == 0) {
        store2(out0pk + (size_t)(TT - 1) * BH + orow, prevPk, true);
        asm volatile("s_waitcnt vmcnt(0)" ::: "memory");
        __syncthreads();
        if (tid == 0) storef(cflags + slot, TT, true);
    }
}

extern "C" void kernel_launch(void* const* d_in, const int* in_sizes, int n_in,
                              void* d_out, int out_size, void* d_ws, size_t ws_size,
                              hipStream_t stream) {
    const float* x    = (const float*)d_in[0];
    const float* Wih0 = (const float*)d_in[1];
    const float* Whh0 = (const float*)d_in[2];
    const float* bih0 = (const float*)d_in[3];
    const float* bhh0 = (const float*)d_in[4];
    const float* Wih1 = (const float*)d_in[5];
    const float* Whh1 = (const float*)d_in[6];
    const float* bih1 = (const float*)d_in[7];
    const float* bhh1 = (const float*)d_in[8];

    float* out    = (float*)d_out;
    uint*  out0pk = (uint*)d_ws;                   // [T,B,H] packed layer-0 h (64 MB)
    uint*  hring  = out0pk + TBH;                  // [4][3][32*512] L2-local rings
    int*   ctrl   = (int*)(hring + 4 * 3 * 16384); // xccTab[128] lflags[256] cflags[128]

    // reset control block each call: xccTab=-1, all flags=-1
    (void)hipMemsetAsync(ctrl, 0xFF, 512 * sizeof(int), stream);

    void* args[] = { (void*)&x, (void*)&Wih0, (void*)&Whh0, (void*)&bih0, (void*)&bhh0,
                     (void*)&Wih1, (void*)&Whh1, (void*)&bih1, (void*)&bhh1,
                     (void*)&out, (void*)&out0pk, (void*)&hring, (void*)&ctrl };
    hipError_t e = hipLaunchCooperativeKernel((const void*)lstm_persist,
                                              dim3(256), dim3(256), args, 0, stream);
    if (e != hipSuccess) {
        // fallback: plain launch — viable because 35KB LDS / ~220 VGPR keeps
        // full-grid residency (all 256 WGs fit 1/CU)
        lstm_persist<<<dim3(256), dim3(256), 0, stream>>>(
            x, Wih0, Whh0, bih0, bhh0, Wih1, Whh1, bih1, bhh1,
            out, out0pk, hring, ctrl);
    }
}